// Round 1
// baseline (6103.693 us; speedup 1.0000x reference)
//
#include <hip/hip_runtime.h>
#include <hip/hip_bf16.h>

#define SEQ   256
#define BATCH 256
#define KDIM  1024   // C_IN * R_IN
#define ODIM  1024   // C_OUT * R_OUT

typedef __bf16 bf16_t;
typedef bf16_t bf16x4 __attribute__((ext_vector_type(4)));
typedef bf16_t bf16x8 __attribute__((ext_vector_type(8)));
typedef float  f32x4  __attribute__((ext_vector_type(4)));

// ---------------------------------------------------------------------------
// fp32 -> bf16 weight conversion: 6 x (1024 x 1024), output contiguous in ws.
// Order: Wrx, Wrh, Wux, Wuh, Wcx, Wch  (even = x-operand, odd = h-operand)
// ---------------------------------------------------------------------------
__global__ __launch_bounds__(1024) void convert_weights(
    const float* __restrict__ wrx, const float* __restrict__ wrh,
    const float* __restrict__ wux, const float* __restrict__ wuh,
    const float* __restrict__ wcx, const float* __restrict__ wch,
    bf16_t* __restrict__ out)
{
    const int i = blockIdx.x * 1024 + threadIdx.x;   // 0 .. 6*2^20-1
    const int w = i >> 20;
    const int j = i & 1048575;
    const float* src;
    switch (w) {
        case 0:  src = wrx; break;
        case 1:  src = wrh; break;
        case 2:  src = wux; break;
        case 3:  src = wuh; break;
        case 4:  src = wcx; break;
        default: src = wch; break;
    }
    out[i] = (bf16_t)src[j];
}

// ---------------------------------------------------------------------------
// One GRU timestep: 6 fused GEMMs (256x1024 x 1024x1024 each, bf16 MFMA)
// + gate elementwise. Tile: BM=32 (batch) x BN=32 (out-feature) x BK=64.
// Block = 256 threads = 4 waves, one 16x16 quadrant per wave, 6 accumulators.
// Grid (32 n-tiles, 8 m-tiles): n fastest => stable n-slice -> XCD mapping.
// ---------------------------------------------------------------------------
__global__ __launch_bounds__(256) void gru_step(
    const float* __restrict__ x_t,    // (256, 1024) fp32
    const float* __restrict__ h_in,   // (256, 1024) fp32
    float* __restrict__ h_out,        // (256, 1024) fp32
    float* __restrict__ hseq_out,     // d_out + t*256*1024
    float* __restrict__ hlast_out,    // d_out tail (t == SEQ-1) or nullptr
    const bf16_t* __restrict__ wb,    // 6 x (1024 out, 1024 in) bf16
    const float* __restrict__ brx, const float* __restrict__ brh,
    const float* __restrict__ bux, const float* __restrict__ buh,
    const float* __restrict__ bcx, const float* __restrict__ bch)
{
    __shared__ bf16_t sA[2][32][72];   // [x|h][m][k]  (+8 pad: 144B row stride)
    __shared__ bf16_t sB[6][32][72];   // [w][n][k]

    const int tid    = threadIdx.x;
    const int m_base = blockIdx.y * 32;
    const int n_base = blockIdx.x * 32;

    const int lane = tid & 63;
    const int wv   = tid >> 6;
    const int wm   = (wv >> 1) * 16;   // wave quadrant row offset
    const int wn   = (wv & 1) * 16;    // wave quadrant col offset
    const int lr   = lane & 15;
    const int quad = lane >> 4;

    f32x4 acc[6];
#pragma unroll
    for (int w = 0; w < 6; ++w) acc[w] = (f32x4){0.f, 0.f, 0.f, 0.f};

    // A staging: 512 float4 slots per matrix; thread handles slots tid, tid+256
    const int ar0 = tid >> 4;            // rows 0..15
    const int ac0 = (tid & 15) * 4;      // k-col (multiple of 4)
    const int ar1 = ar0 + 16;            // rows 16..31
    // B staging: 256 x 8-elem slots per weight tile
    const int br_ = tid >> 3;            // row 0..31
    const int bc_ = (tid & 7) * 8;       // k-col (multiple of 8)

    for (int kk = 0; kk < 16; ++kk) {
        const int k0 = kk * 64;
        __syncthreads();
        {
            const float4 vx0 = *(const float4*)&x_t[(size_t)(m_base + ar0) * KDIM + k0 + ac0];
            const float4 vx1 = *(const float4*)&x_t[(size_t)(m_base + ar1) * KDIM + k0 + ac0];
            const float4 vh0 = *(const float4*)&h_in[(size_t)(m_base + ar0) * KDIM + k0 + ac0];
            const float4 vh1 = *(const float4*)&h_in[(size_t)(m_base + ar1) * KDIM + k0 + ac0];
            *(bf16x4*)&sA[0][ar0][ac0] = (bf16x4){(bf16_t)vx0.x, (bf16_t)vx0.y, (bf16_t)vx0.z, (bf16_t)vx0.w};
            *(bf16x4*)&sA[0][ar1][ac0] = (bf16x4){(bf16_t)vx1.x, (bf16_t)vx1.y, (bf16_t)vx1.z, (bf16_t)vx1.w};
            *(bf16x4*)&sA[1][ar0][ac0] = (bf16x4){(bf16_t)vh0.x, (bf16_t)vh0.y, (bf16_t)vh0.z, (bf16_t)vh0.w};
            *(bf16x4*)&sA[1][ar1][ac0] = (bf16x4){(bf16_t)vh1.x, (bf16_t)vh1.y, (bf16_t)vh1.z, (bf16_t)vh1.w};
        }
#pragma unroll
        for (int w = 0; w < 6; ++w) {
            bf16x8 v = *(const bf16x8*)&wb[((size_t)w << 20) + (size_t)(n_base + br_) * KDIM + k0 + bc_];
            *(bf16x8*)&sB[w][br_][bc_] = v;
        }
        __syncthreads();

#pragma unroll
        for (int ks = 0; ks < 2; ++ks) {
            const int koff = ks * 32 + quad * 8;
            const bf16x8 a_x = *(const bf16x8*)&sA[0][wm + lr][koff];
            const bf16x8 a_h = *(const bf16x8*)&sA[1][wm + lr][koff];
            const bf16x8 b0  = *(const bf16x8*)&sB[0][wn + lr][koff];
            const bf16x8 b1  = *(const bf16x8*)&sB[1][wn + lr][koff];
            const bf16x8 b2  = *(const bf16x8*)&sB[2][wn + lr][koff];
            const bf16x8 b3  = *(const bf16x8*)&sB[3][wn + lr][koff];
            const bf16x8 b4  = *(const bf16x8*)&sB[4][wn + lr][koff];
            const bf16x8 b5  = *(const bf16x8*)&sB[5][wn + lr][koff];
            acc[0] = __builtin_amdgcn_mfma_f32_16x16x32_bf16(a_x, b0, acc[0], 0, 0, 0);
            acc[1] = __builtin_amdgcn_mfma_f32_16x16x32_bf16(a_h, b1, acc[1], 0, 0, 0);
            acc[2] = __builtin_amdgcn_mfma_f32_16x16x32_bf16(a_x, b2, acc[2], 0, 0, 0);
            acc[3] = __builtin_amdgcn_mfma_f32_16x16x32_bf16(a_h, b3, acc[3], 0, 0, 0);
            acc[4] = __builtin_amdgcn_mfma_f32_16x16x32_bf16(a_x, b4, acc[4], 0, 0, 0);
            acc[5] = __builtin_amdgcn_mfma_f32_16x16x32_bf16(a_h, b5, acc[5], 0, 0, 0);
        }
    }

    // Epilogue: C/D layout row = quad*4 + reg, col = lane&15 (m89-verified)
    const int o = n_base + wn + lr;
    const float vbrx = brx[o], vbrh = brh[o];
    const float vbux = bux[o], vbuh = buh[o];
    const float vbcx = bcx[o], vbch = bch[o];

#pragma unroll
    for (int r = 0; r < 4; ++r) {
        const int b   = m_base + wm + quad * 4 + r;
        const int idx = b * ODIM + o;
        const float h_old = h_in[idx];
        const float pre_r = acc[0][r] + acc[1][r] + vbrx + vbrh;
        const float rg    = 1.f / (1.f + __expf(-pre_r));
        const float pre_z = acc[2][r] + acc[3][r] + vbux + vbuh;
        const float zg    = 1.f / (1.f + __expf(-pre_z));
        const float pre_n = acc[4][r] + vbcx + rg * (acc[5][r] + vbch);
        const float ng    = tanhf(pre_n);
        const float h_new = (1.f - zg) * ng + zg * h_old;
        h_out[idx]    = h_new;
        hseq_out[idx] = h_new;
        if (hlast_out) hlast_out[idx] = h_new;
    }
}

// ---------------------------------------------------------------------------
extern "C" void kernel_launch(void* const* d_in, const int* in_sizes, int n_in,
                              void* d_out, int out_size, void* d_ws, size_t ws_size,
                              hipStream_t stream)
{
    const float* x   = (const float*)d_in[0];
    const float* h0  = (const float*)d_in[1];
    const float* Wrx = (const float*)d_in[2];
    const float* brx = (const float*)d_in[3];
    const float* Wrh = (const float*)d_in[4];
    const float* brh = (const float*)d_in[5];
    const float* Wux = (const float*)d_in[6];
    const float* bux = (const float*)d_in[7];
    const float* Wuh = (const float*)d_in[8];
    const float* buh = (const float*)d_in[9];
    const float* Wcx = (const float*)d_in[10];
    const float* bcx = (const float*)d_in[11];
    const float* Wch = (const float*)d_in[12];
    const float* bch = (const float*)d_in[13];

    float* out   = (float*)d_out;
    float* hseq  = out;
    float* hlast = out + (size_t)SEQ * BATCH * ODIM;

    // workspace layout: 12 MB bf16 weights | 1 MB h ping | 1 MB h pong
    bf16_t* wb    = (bf16_t*)d_ws;
    float*  hbuf0 = (float*)((char*)d_ws + (size_t)6 * 1048576 * sizeof(bf16_t));
    float*  hbuf1 = hbuf0 + (size_t)BATCH * ODIM;

    convert_weights<<<6144, 1024, 0, stream>>>(Wrx, Wrh, Wux, Wuh, Wcx, Wch, wb);
    hipMemcpyAsync(hbuf0, h0, (size_t)BATCH * ODIM * sizeof(float),
                   hipMemcpyDeviceToDevice, stream);

    dim3 grid(32, 8);   // (n-tiles, m-tiles): n fastest for XCD-stable weights
    float* hb[2] = {hbuf0, hbuf1};
    for (int t = 0; t < SEQ; ++t) {
        gru_step<<<grid, 256, 0, stream>>>(
            x + (size_t)t * BATCH * KDIM,
            hb[t & 1], hb[(t + 1) & 1],
            hseq + (size_t)t * BATCH * ODIM,
            (t == SEQ - 1) ? hlast : nullptr,
            wb, brx, brh, bux, buh, bcx, bch);
    }
}